// Round 7
// baseline (3514.430 us; speedup 1.0000x reference)
//
#include <hip/hip_runtime.h>
#include <cstddef>

#define BB 4
#define TT 1024
#define DMODEL 512
#define DFF 2048
#define NHEAD 8
#define HDIM 64
#define NTOK (BB*TT)
#define NLAYER 6
#define MFOUT 256

typedef __attribute__((ext_vector_type(8))) _Float16 f16x8;
typedef __attribute__((ext_vector_type(8))) short bf16x8;
typedef __attribute__((ext_vector_type(4))) float f32x4;
#define MFMAH(a,b,c) __builtin_amdgcn_mfma_f32_16x16x32_f16(a,b,c,0,0,0)
#define MFMAB(a,b,c) __builtin_amdgcn_mfma_f32_16x16x32_bf16(a,b,c,0,0,0)

union F16U { _Float16 h; unsigned short u; };

__device__ __forceinline__ unsigned f2bf(float f) {
    union { float f; unsigned u; } v; v.f = f;
    return (v.u + 0x7FFFu + ((v.u >> 16) & 1u)) >> 16;
}
__device__ __forceinline__ float bf2f(unsigned h) {
    union { unsigned u; float f; } v; v.u = h << 16;
    return v.f;
}
__device__ __forceinline__ unsigned short f16u(float v) {
    F16U t; t.h = (_Float16)v; return t.u;
}

#define MODE_F32  0   // fp32 out (+optional res)
#define MODE_BF   1   // bf16 hi/lo pair
#define MODE_QKV  5   // n<512 -> Q(f16 hi+mid*1024), <1024 -> K(f16), else V(f16 hi/lo)

// ---------------- weight convert: fp32 [K][N] -> bf16 hi/lo [N][K] ----------------
__global__ __launch_bounds__(256)
void wcvt(const float* __restrict__ W, unsigned short* __restrict__ Wh,
          unsigned short* __restrict__ Wl, int N, int K)
{
    __shared__ unsigned short Hs[64][72];
    __shared__ unsigned short Ls[64][72];
    const int tid = threadIdx.x;
    const int n0 = blockIdx.x * 64, k0 = blockIdx.y * 64;
    #pragma unroll
    for (int i = 0; i < 4; i++) {
        const int idx = tid + i * 256;
        const int r = idx >> 4, c4 = (idx & 15) * 4;
        const float4 v = *(const float4*)&W[(size_t)(k0 + r) * N + n0 + c4];
        const float va[4] = {v.x, v.y, v.z, v.w};
        #pragma unroll
        for (int j = 0; j < 4; j++) {
            const unsigned h = f2bf(va[j]);
            Hs[c4 + j][r] = (unsigned short)h;
            Ls[c4 + j][r] = (unsigned short)f2bf(va[j] - bf2f(h));
        }
    }
    __syncthreads();
    #pragma unroll
    for (int i = 0; i < 2; i++) {
        const int idx = tid + i * 256;
        const int r = idx >> 3, c8 = (idx & 7) * 8;
        *(uint4*)&Wh[(size_t)(n0 + r) * K + k0 + c8] = *(const uint4*)&Hs[r][c8];
        *(uint4*)&Wl[(size_t)(n0 + r) * K + k0 + c8] = *(const uint4*)&Ls[r][c8];
    }
}

// ---------------- zero-LDS pair GEMM, bf16 hi/lo 3-pass ----------------
// A: bf16 pair [M][K]; W: bf16 pair [N][K] (pre-converted). Tile 64x64, 4 waves (2x2).
// Fragments load DIRECT from global (L2-resident); no LDS, no barriers.
__global__ __launch_bounds__(256, 3)
void gemm_p(const unsigned short* __restrict__ Ah, const unsigned short* __restrict__ Al,
            const unsigned short* __restrict__ Wh, const unsigned short* __restrict__ Wl,
            const float* __restrict__ bias, const float* __restrict__ alpha,
            const float* __restrict__ res, float* __restrict__ outf,
            unsigned short* __restrict__ o1, unsigned short* __restrict__ o2,
            unsigned short* __restrict__ o3, unsigned short* __restrict__ o4,
            unsigned short* __restrict__ o5, int N, int K, int mode)
{
    const int tid = threadIdx.x;
    const int lane = tid & 63, w = tid >> 6;
    const int wm = w >> 1, wn = w & 1;
    const int quad = lane >> 4, c = lane & 15;
    const int m0 = blockIdx.y * 64, n0 = blockIdx.x * 64;
    const size_t a0 = (size_t)(m0 + wm * 32 + c) * K + quad * 8;
    const size_t a1 = a0 + (size_t)16 * K;
    const size_t b0 = (size_t)(n0 + wn * 32 + c) * K + quad * 8;
    const size_t b1 = b0 + (size_t)16 * K;

    f32x4 acc[2][2];
    #pragma unroll
    for (int mi = 0; mi < 2; mi++)
        #pragma unroll
        for (int ni = 0; ni < 2; ni++) { acc[mi][ni][0]=0.f; acc[mi][ni][1]=0.f; acc[mi][ni][2]=0.f; acc[mi][ni][3]=0.f; }

    #pragma unroll 2
    for (int k0 = 0; k0 < K; k0 += 32) {
        const bf16x8 ah0 = *(const bf16x8*)&Ah[a0 + k0];
        const bf16x8 ah1 = *(const bf16x8*)&Ah[a1 + k0];
        const bf16x8 al0 = *(const bf16x8*)&Al[a0 + k0];
        const bf16x8 al1 = *(const bf16x8*)&Al[a1 + k0];
        const bf16x8 bh0 = *(const bf16x8*)&Wh[b0 + k0];
        const bf16x8 bh1 = *(const bf16x8*)&Wh[b1 + k0];
        const bf16x8 bl0 = *(const bf16x8*)&Wl[b0 + k0];
        const bf16x8 bl1 = *(const bf16x8*)&Wl[b1 + k0];
        acc[0][0] = MFMAB(ah0, bh0, acc[0][0]);
        acc[0][1] = MFMAB(ah0, bh1, acc[0][1]);
        acc[1][0] = MFMAB(ah1, bh0, acc[1][0]);
        acc[1][1] = MFMAB(ah1, bh1, acc[1][1]);
        acc[0][0] = MFMAB(al0, bh0, acc[0][0]);
        acc[0][1] = MFMAB(al0, bh1, acc[0][1]);
        acc[1][0] = MFMAB(al1, bh0, acc[1][0]);
        acc[1][1] = MFMAB(al1, bh1, acc[1][1]);
        acc[0][0] = MFMAB(ah0, bl0, acc[0][0]);
        acc[0][1] = MFMAB(ah0, bl1, acc[0][1]);
        acc[1][0] = MFMAB(ah1, bl0, acc[1][0]);
        acc[1][1] = MFMAB(ah1, bl1, acc[1][1]);
    }
    const float alv = alpha ? alpha[0] : 0.f;
    #pragma unroll
    for (int mi = 0; mi < 2; mi++)
        #pragma unroll
        for (int ni = 0; ni < 2; ni++) {
            const int gn = n0 + wn * 32 + ni * 16 + c;
            const float bv = bias ? bias[gn] : 0.f;
            #pragma unroll
            for (int r = 0; r < 4; r++) {
                const int gm = m0 + wm * 32 + mi * 16 + quad * 4 + r;
                float v = acc[mi][ni][r] + bv;
                if (alpha) v = (v >= 0.f) ? v : alv * v;
                if (mode == MODE_F32) {
                    const size_t oix = (size_t)gm * N + gn;
                    if (res) v += res[oix];
                    outf[oix] = v;
                } else if (mode == MODE_BF) {
                    const size_t oix = (size_t)gm * N + gn;
                    const unsigned h = f2bf(v);
                    o1[oix] = (unsigned short)h;
                    o2[oix] = (unsigned short)f2bf(v - bf2f(h));
                } else { // MODE_QKV
                    const int seg = gn >> 9;           // uniform per block (64 | 512)
                    const size_t qix = (size_t)gm * 512 + (gn & 511);
                    if (seg == 0) {
                        F16U t; t.h = (_Float16)v;
                        o1[qix] = t.u;
                        o2[qix] = f16u((v - (float)t.h) * 1024.f);
                    } else if (seg == 1) {
                        o3[qix] = f16u(v);
                    } else {
                        F16U t; t.h = (_Float16)v;
                        o4[qix] = t.u;
                        o5[qix] = f16u(v - (float)t.h);
                    }
                }
            }
        }
}

// ---------------- LayerNorm: one wave per token -> bf16 hi/lo pair ----------------
__global__ __launch_bounds__(64)
void ln_kernel(const float* __restrict__ x, const float* __restrict__ g,
               const float* __restrict__ b, unsigned short* __restrict__ oh,
               unsigned short* __restrict__ ol)
{
    const int token = blockIdx.x;
    const int lane = threadIdx.x;
    const float* row = x + (size_t)token * DMODEL;
    float v[8];
    *(float4*)&v[0] = *(const float4*)&row[lane * 4];
    *(float4*)&v[4] = *(const float4*)&row[256 + lane * 4];
    float s = 0.f, s2 = 0.f;
    #pragma unroll
    for (int i = 0; i < 8; i++) { s += v[i]; s2 += v[i] * v[i]; }
    #pragma unroll
    for (int off = 1; off < 64; off <<= 1) {
        s  += __shfl_xor(s, off);
        s2 += __shfl_xor(s2, off);
    }
    const float mean = s * (1.f / DMODEL);
    const float var  = s2 * (1.f / DMODEL) - mean * mean;
    const float rstd = rsqrtf(var + 1e-5f);
    #pragma unroll
    for (int hh = 0; hh < 2; hh++) {
        const int base = hh * 256 + lane * 4;
        const float4 gv = *(const float4*)&g[base];
        const float4 bv = *(const float4*)&b[base];
        float o[4];
        o[0] = (v[hh*4+0] - mean) * rstd * gv.x + bv.x;
        o[1] = (v[hh*4+1] - mean) * rstd * gv.y + bv.y;
        o[2] = (v[hh*4+2] - mean) * rstd * gv.z + bv.z;
        o[3] = (v[hh*4+3] - mean) * rstd * gv.w + bv.w;
        ushort4 ph, pl;
        unsigned short* php = (unsigned short*)&ph;
        unsigned short* plp = (unsigned short*)&pl;
        #pragma unroll
        for (int j = 0; j < 4; j++) {
            const unsigned hb = f2bf(o[j]);
            php[j] = (unsigned short)hb;
            plp[j] = (unsigned short)f2bf(o[j] - bf2f(hb));
        }
        *(ushort4*)&oh[(size_t)token * DMODEL + base] = ph;
        *(ushort4*)&ol[(size_t)token * DMODEL + base] = pl;
    }
}

// ---------------- fp32 -> bf16 hi/lo pair (elementwise) ----------------
__global__ __launch_bounds__(256)
void cvt_pair(const float* __restrict__ x, unsigned short* __restrict__ oh,
              unsigned short* __restrict__ ol)
{
    const int idx = (blockIdx.x * 256 + threadIdx.x) * 4;
    const float4 v = *(const float4*)&x[idx];
    const float va[4] = {v.x, v.y, v.z, v.w};
    ushort4 ph, pl;
    unsigned short* php = (unsigned short*)&ph;
    unsigned short* plp = (unsigned short*)&pl;
    #pragma unroll
    for (int j = 0; j < 4; j++) {
        const unsigned hb = f2bf(va[j]);
        php[j] = (unsigned short)hb;
        plp[j] = (unsigned short)f2bf(va[j] - bf2f(hb));
    }
    *(ushort4*)&oh[idx] = ph;
    *(ushort4*)&ol[idx] = pl;
}

// ---------------- concat [x | mask] -> bf16 pair, [4096][1024] ----------------
__global__ __launch_bounds__(256)
void cvt_cat(const float* __restrict__ x, const float* __restrict__ mask,
             unsigned short* __restrict__ oh, unsigned short* __restrict__ ol)
{
    const int idx = (blockIdx.x * 256 + threadIdx.x) * 4;
    const int row = idx >> 10, col = idx & 1023;
    const float* src = (col < 512) ? &x[(size_t)row * 512 + col]
                                   : &mask[(size_t)row * 512 + col - 512];
    const float4 v = *(const float4*)src;
    const float va[4] = {v.x, v.y, v.z, v.w};
    ushort4 ph, pl;
    unsigned short* php = (unsigned short*)&ph;
    unsigned short* plp = (unsigned short*)&pl;
    #pragma unroll
    for (int j = 0; j < 4; j++) {
        const unsigned hb = f2bf(va[j]);
        php[j] = (unsigned short)hb;
        plp[j] = (unsigned short)f2bf(va[j] - bf2f(hb));
    }
    *(ushort4*)&oh[idx] = ph;
    *(ushort4*)&ol[idx] = pl;
}

// ---------------- attention key-validity mask ----------------
__global__ __launch_bounds__(64)
void mask_kernel(const float* __restrict__ mask_in, float* __restrict__ mk)
{
    const int token = blockIdx.x;
    const int lane = threadIdx.x;
    const float* row = mask_in + (size_t)token * DMODEL;
    const float4 a = *(const float4*)&row[lane * 4];
    const float4 c = *(const float4*)&row[256 + lane * 4];
    float s = a.x + a.y + a.z + a.w + c.x + c.y + c.z + c.w;
    #pragma unroll
    for (int off = 1; off < 64; off <<= 1) s += __shfl_xor(s, off);
    if (lane == 0) mk[token] = (s > 0.f) ? 0.f : -1e9f;
}

// ---------------- relative position table E -> f16 hi/lo (2047, 64) ----------------
__global__ __launch_bounds__(64)
void e_kernel(const float* __restrict__ w1, const float* __restrict__ b1,
              const float* __restrict__ a1, const float* __restrict__ w2,
              const float* __restrict__ b2,
              unsigned short* __restrict__ Ehi, unsigned short* __restrict__ Elo)
{
    __shared__ float t1[DMODEL];
    const int r = blockIdx.x;
    const int lane = threadIdx.x;
    const float rel = (float)r - 1023.f;
    const float al = a1[0];
    for (int j = lane; j < DMODEL; j += 64) {
        float v = rel * w1[j] + b1[j];
        t1[j] = (v >= 0.f) ? v : al * v;
    }
    __syncthreads();
    float acc = b2[lane];
    for (int j = 0; j < DMODEL; j++)
        acc = fmaf(t1[j], w2[j * HDIM + lane], acc);
    F16U t; t.h = (_Float16)acc;
    Ehi[(size_t)r * HDIM + lane] = t.u;
    Elo[(size_t)r * HDIM + lane] = f16u(acc - (float)t.h);
}

// ---------------- keyframe encoder layer 1 (K=2) -> bf16 pair ----------------
__global__ __launch_bounds__(256)
void kf1_kernel(const float* __restrict__ p, const float* __restrict__ w1,
                const float* __restrict__ b1, const float* __restrict__ a1,
                unsigned short* __restrict__ oh, unsigned short* __restrict__ ol)
{
    const int idx = blockIdx.x * 256 + threadIdx.x;
    const int m = idx >> 9, n = idx & 511;
    float v = fmaf(p[m*2], w1[n], fmaf(p[m*2+1], w1[DMODEL + n], b1[n]));
    v = (v >= 0.f) ? v : a1[0] * v;
    const unsigned hb = f2bf(v);
    oh[idx] = (unsigned short)hb;
    ol[idx] = (unsigned short)f2bf(v - bf2f(hb));
}

// ---------------- MFMA flash attention, f16 hi/lo, pre-converted inputs ----------------
// Q/K/V arrive f16 (Q: hi+mid*1024, K: single, V: hi+lo). O out as bf16 pair.
// RACE FIX: __threadfence_block() between same-wave cross-lane P LDS writes and reads
// (prevents compiler hoisting the ds_read above the ds_write; HW DS is in-order per wave).
__global__ __launch_bounds__(256, 2)
void attn_mfma(const _Float16* __restrict__ qhg, const _Float16* __restrict__ qmg,
               const _Float16* __restrict__ kg, const _Float16* __restrict__ vhg,
               const _Float16* __restrict__ vlg, const _Float16* __restrict__ Ehi,
               const _Float16* __restrict__ Elo, const float* __restrict__ mk,
               unsigned short* __restrict__ obh, unsigned short* __restrict__ obl)
{
    __shared__ __align__(16) _Float16 Ks [64*72];
    __shared__ __align__(16) _Float16 Vth[64*72];
    __shared__ __align__(16) _Float16 Vtl[64*72];
    __shared__ __align__(16) _Float16 Phs[64*72];
    __shared__ __align__(16) _Float16 Pls[64*72];

    const int tid = threadIdx.x;
    const int lane = tid & 63;
    const int w = tid >> 6;
    const int quad = lane >> 4;
    const int c = lane & 15;
    const int q0 = blockIdx.x * 64;
    const int hh = blockIdx.y;
    const int bb = blockIdx.z;
    const size_t base = (size_t)bb * TT * DMODEL + (size_t)hh * HDIM;
    const float* mkp = mk + bb * TT;

    f16x8 qh[2], qm[2];
    {
        const size_t qrow = base + (size_t)(q0 + 16 * w + c) * DMODEL;
        #pragma unroll
        for (int s = 0; s < 2; s++) {
            qh[s] = *(const f16x8*)&qhg[qrow + s * 32 + quad * 8];
            qm[s] = *(const f16x8*)&qmg[qrow + s * 32 + quad * 8];
        }
    }

    f32x4 O[4];
    #pragma unroll
    for (int dt = 0; dt < 4; dt++) { O[dt][0]=0.f; O[dt][1]=0.f; O[dt][2]=0.f; O[dt][3]=0.f; }
    float mrun[4] = {-1e30f, -1e30f, -1e30f, -1e30f};
    float lrun[4] = {0.f, 0.f, 0.f, 0.f};
    const int Jb = 48 - 16 * w;

    for (int kt = 0; kt < 16; kt++) {
        const int k0 = kt * 64;
        const size_t kvbase = base + (size_t)k0 * DMODEL;
        const int rbase = k0 - q0 + 960;
        #pragma unroll
        for (int i = 0; i < 2; i++) {
            const int idx = tid + i * 256;
            const int r = idx >> 3, c8 = (idx & 7) * 8;
            *(uint4*)&Ks[r * 72 + c8] = *(const uint4*)&kg[kvbase + (size_t)r * DMODEL + c8];
            const f16x8 vh8 = *(const f16x8*)&vhg[kvbase + (size_t)r * DMODEL + c8];
            const f16x8 vl8 = *(const f16x8*)&vlg[kvbase + (size_t)r * DMODEL + c8];
            #pragma unroll
            for (int j = 0; j < 8; j++) {
                Vth[(c8 + j) * 72 + r] = vh8[j];
                Vtl[(c8 + j) * 72 + r] = vl8[j];
            }
        }
        __syncthreads();

        f32x4 S[4];
        #pragma unroll
        for (int t = 0; t < 4; t++) { S[t][0]=0.f; S[t][1]=0.f; S[t][2]=0.f; S[t][3]=0.f; }
        #pragma unroll
        for (int t = 0; t < 4; t++)
            #pragma unroll
            for (int s = 0; s < 2; s++) {
                const f16x8 kf = *(const f16x8*)&Ks[(16*t + c) * 72 + s*32 + quad*8];
                S[t] = MFMAH(qh[s], kf, S[t]);
            }
        f32x4 R[5], R2[5];
        #pragma unroll
        for (int u = 0; u < 5; u++) {
            R[u][0]=0.f; R[u][1]=0.f; R[u][2]=0.f; R[u][3]=0.f;
            R2[u][0]=0.f; R2[u][1]=0.f; R2[u][2]=0.f; R2[u][3]=0.f;
        }
        #pragma unroll
        for (int u = 0; u < 5; u++) {
            int gr = rbase + Jb + 16 * u + c;
            gr = gr < 0 ? 0 : (gr > 2046 ? 2046 : gr);
            const size_t eb = (size_t)gr * HDIM;
            const f16x8 eh0 = *(const f16x8*)&Ehi[eb + quad * 8];
            const f16x8 eh1 = *(const f16x8*)&Ehi[eb + 32 + quad * 8];
            const f16x8 el0 = *(const f16x8*)&Elo[eb + quad * 8];
            const f16x8 el1 = *(const f16x8*)&Elo[eb + 32 + quad * 8];
            R[u]  = MFMAH(qh[0], eh0, R[u]);
            R[u]  = MFMAH(qh[1], eh1, R[u]);
            R[u]  = MFMAH(qh[0], el0, R[u]);
            R[u]  = MFMAH(qh[1], el1, R[u]);
            R2[u] = MFMAH(qm[0], eh0, R2[u]);
            R2[u] = MFMAH(qm[1], eh1, R2[u]);
        }
        #pragma unroll
        for (int u = 0; u < 5; u++)
            #pragma unroll
            for (int r = 0; r < 4; r++)
                R[u][r] = fmaf(R2[u][r], 9.765625e-4f, R[u][r]);
        float bp[4][5];
        #pragma unroll
        for (int r = 0; r < 4; r++) {
            const int q = quad * 4 + r;
            const int srcl = (quad << 4) | ((c - q + 15) & 15);
            #pragma unroll
            for (int u = 0; u < 5; u++)
                bp[r][u] = __int_as_float(__builtin_amdgcn_ds_bpermute(srcl << 2, __float_as_int(R[u][r])));
        }
        float mkv[4];
        #pragma unroll
        for (int t = 0; t < 4; t++) mkv[t] = mkp[k0 + 16*t + c];
        float scv[4][4];
        float tmax[4] = {-3e38f, -3e38f, -3e38f, -3e38f};
        #pragma unroll
        for (int t = 0; t < 4; t++)
            #pragma unroll
            for (int r = 0; r < 4; r++) {
                const int q = quad*4 + r;
                const int jj = 16*t + c - q + 15;
                const float rv = ((jj >> 4) == t) ? bp[r][t] : bp[r][t+1];
                const float v = (S[t][r] + rv) * 0.125f + mkv[t];
                scv[t][r] = v;
                tmax[r] = fmaxf(tmax[r], v);
            }
        #pragma unroll
        for (int r = 0; r < 4; r++) {
            tmax[r] = fmaxf(tmax[r], __shfl_xor(tmax[r], 1));
            tmax[r] = fmaxf(tmax[r], __shfl_xor(tmax[r], 2));
            tmax[r] = fmaxf(tmax[r], __shfl_xor(tmax[r], 4));
            tmax[r] = fmaxf(tmax[r], __shfl_xor(tmax[r], 8));
        }
        float corr[4];
        #pragma unroll
        for (int r = 0; r < 4; r++) {
            const float mn = fmaxf(mrun[r], tmax[r]);
            corr[r] = __expf(mrun[r] - mn);
            mrun[r] = mn;
            lrun[r] *= corr[r];
        }
        #pragma unroll
        for (int dt = 0; dt < 4; dt++)
            #pragma unroll
            for (int r = 0; r < 4; r++) O[dt][r] *= corr[r];
        float psum[4] = {0.f, 0.f, 0.f, 0.f};
        #pragma unroll
        for (int t = 0; t < 4; t++)
            #pragma unroll
            for (int r = 0; r < 4; r++) {
                const float p = __expf(scv[t][r] - mrun[r]);
                psum[r] += p;
                const _Float16 hp = (_Float16)p;
                Phs[(w*16 + quad*4 + r)*72 + 16*t + c] = hp;
                Pls[(w*16 + quad*4 + r)*72 + 16*t + c] = (_Float16)(p - (float)hp);
            }
        #pragma unroll
        for (int r = 0; r < 4; r++) {
            psum[r] += __shfl_xor(psum[r], 1);
            psum[r] += __shfl_xor(psum[r], 2);
            psum[r] += __shfl_xor(psum[r], 4);
            psum[r] += __shfl_xor(psum[r], 8);
            lrun[r] += psum[r];
        }
        __threadfence_block();   // order same-wave cross-lane P LDS write -> read
        f16x8 pfh[2], pfl[2];
        #pragma unroll
        for (int s = 0; s < 2; s++) {
            pfh[s] = *(const f16x8*)&Phs[(w*16 + c)*72 + s*32 + quad*8];
            pfl[s] = *(const f16x8*)&Pls[(w*16 + c)*72 + s*32 + quad*8];
        }
        #pragma unroll
        for (int dt = 0; dt < 4; dt++)
            #pragma unroll
            for (int s = 0; s < 2; s++) {
                const f16x8 vhf = *(const f16x8*)&Vth[(16*dt + c)*72 + s*32 + quad*8];
                const f16x8 vlf = *(const f16x8*)&Vtl[(16*dt + c)*72 + s*32 + quad*8];
                O[dt] = MFMAH(pfh[s], vhf, O[dt]);
                O[dt] = MFMAH(pfl[s], vhf, O[dt]);
                O[dt] = MFMAH(pfh[s], vlf, O[dt]);
            }
        __syncthreads();
    }
    float inv[4];
    #pragma unroll
    for (int r = 0; r < 4; r++) inv[r] = 1.f / lrun[r];
    #pragma unroll
    for (int dt = 0; dt < 4; dt++)
        #pragma unroll
        for (int r = 0; r < 4; r++) {
            const float v = O[dt][r] * inv[r];
            const size_t oix = base + (size_t)(q0 + 16*w + quad*4 + r) * DMODEL + 16*dt + c;
            const unsigned hb = f2bf(v);
            obh[oix] = (unsigned short)hb;
            obl[oix] = (unsigned short)f2bf(v - bf2f(hb));
        }
}

extern "C" void kernel_launch(void* const* d_in, const int* in_sizes, int n_in,
                              void* d_out, int out_size, void* d_ws, size_t ws_size,
                              hipStream_t stream)
{
    const float* x       = (const float*)d_in[0];
    const float* mask_in = (const float*)d_in[1];
    const float* p_kf    = (const float*)d_in[2];
    const float* enc_w1  = (const float*)d_in[3];
    const float* enc_b1  = (const float*)d_in[4];
    const float* enc_a1  = (const float*)d_in[5];
    const float* enc_w2  = (const float*)d_in[6];
    const float* enc_b2  = (const float*)d_in[7];
    const float* enc_a2  = (const float*)d_in[8];
    const float* kf_w1   = (const float*)d_in[9];
    const float* kf_b1   = (const float*)d_in[10];
    const float* kf_a    = (const float*)d_in[11];
    const float* kf_w2   = (const float*)d_in[12];
    const float* kf_b2   = (const float*)d_in[13];
    const float* rel_w1  = (const float*)d_in[14];
    const float* rel_b1  = (const float*)d_in[15];
    const float* rel_a   = (const float*)d_in[16];
    const float* rel_w2  = (const float*)d_in[17];
    const float* rel_b2  = (const float*)d_in[18];
    const float* ln_g    = (const float*)d_in[19];
    const float* ln_b    = (const float*)d_in[20];
    const float* wq      = (const float*)d_in[21];
    const float* wk      = (const float*)d_in[22];
    const float* wv      = (const float*)d_in[23];
    const float* wo      = (const float*)d_in[24];
    const float* wob     = (const float*)d_in[25];
    const float* fw1     = (const float*)d_in[26];
    const float* fb1     = (const float*)d_in[27];
    const float* fa      = (const float*)d_in[28];
    const float* fw2     = (const float*)d_in[29];
    const float* fb2     = (const float*)d_in[30];
    const float* dw1     = (const float*)d_in[31];
    const float* db1     = (const float*)d_in[32];
    const float* da      = (const float*)d_in[33];
    const float* dw2     = (const float*)d_in[34];
    const float* db2     = (const float*)d_in[35];
    float* out = (float*)d_out;

    // ---- workspace layout (bytes), total ~88.6 MB ----
    char* p = (char*)d_ws;
    const size_t SZ_TD  = (size_t)NTOK * DMODEL;      // 2M elems
    float* h = (float*)p;                 p += SZ_TD * 4;
    unsigned short* hnh = (unsigned short*)p; p += SZ_TD * 2;
    unsigned short* hnl = (unsigned short*)p; p += SZ_TD * 2;
    unsigned short* qhg = (unsigned short*)p; p += SZ_TD * 2;
    unsigned short* qmg = (unsigned short*)p; p += SZ_TD * 2;
    unsigned short* kg  = (unsigned short*)p; p += SZ_TD * 2;
    unsigned short* vhg = (unsigned short*)p; p += SZ_TD * 2;
    unsigned short* vlg = (unsigned short*)p; p += SZ_TD * 2;
    unsigned short* obh = (unsigned short*)p; p += SZ_TD * 2;
    unsigned short* obl = (unsigned short*)p; p += SZ_TD * 2;
    unsigned short* midh = (unsigned short*)p; p += (size_t)NTOK * DFF * 2;
    unsigned short* midl = (unsigned short*)p; p += (size_t)NTOK * DFF * 2;
    unsigned short* Ehi = (unsigned short*)p; p += (size_t)2048 * HDIM * 2;
    unsigned short* Elo = (unsigned short*)p; p += (size_t)2048 * HDIM * 2;
    float* mk = (float*)p;                p += (size_t)NTOK * 4;
    // per-layer weight pair buffers (reused each layer; stream-serialized)
    unsigned short* qkvh = (unsigned short*)p; p += (size_t)1536 * 512 * 2;
    unsigned short* qkvl = (unsigned short*)p; p += (size_t)1536 * 512 * 2;
    unsigned short* woh  = (unsigned short*)p; p += (size_t)512 * 512 * 2;
    unsigned short* wol  = (unsigned short*)p; p += (size_t)512 * 512 * 2;
    unsigned short* f1h  = (unsigned short*)p; p += (size_t)2048 * 512 * 2;
    unsigned short* f1l  = (unsigned short*)p; p += (size_t)2048 * 512 * 2;
    unsigned short* f2h  = (unsigned short*)p; p += (size_t)512 * 2048 * 2;
    unsigned short* f2l  = (unsigned short*)p; p += (size_t)512 * 2048 * 2;
    float* pe = (float*)obh;   // 8 MB spanning obh+obl (free during encode)

    const dim3 blk256(256), blk64(64);
    const dim3 gN512(8, 64);     // gemm_p N=512
    const dim3 gQKV(24, 64);     // gemm_p N=1536
    const dim3 gFFN1(32, 64);    // gemm_p N=2048
    const dim3 gN256(4, 64);     // gemm_p N=256
    #define NP nullptr

    e_kernel<<<dim3(2047), blk64, 0, stream>>>(rel_w1, rel_b1, rel_a, rel_w2, rel_b2, Ehi, Elo);
    mask_kernel<<<dim3(NTOK), blk64, 0, stream>>>(mask_in, mk);
    // encode: pre-convert encoder weights into reused slots
    wcvt<<<dim3(8, 8), blk256, 0, stream>>>(kf_w2, woh, wol, 512, 512);
    wcvt<<<dim3(8, 16), blk256, 0, stream>>>(enc_w1, f1h, f1l, 512, 1024);
    wcvt<<<dim3(8, 8), blk256, 0, stream>>>(enc_w2, qkvh, qkvl, 512, 512);
    kf1_kernel<<<dim3(NTOK*DMODEL/256), blk256, 0, stream>>>(p_kf, kf_w1, kf_b1, kf_a, qhg, qmg);
    // pe = kf1_out @ kf_w2 + kf_b2
    gemm_p<<<gN512, blk256, 0, stream>>>(qhg, qmg, woh, wol, kf_b2, NP, NP, pe,
                                         NP, NP, NP, NP, NP, DMODEL, DMODEL, MODE_F32);
    // enc1: [x|mask] -> pair in midh/midl [4096][1024]; out pair -> hnh/hnl
    cvt_cat<<<dim3(NTOK*1024/1024), blk256, 0, stream>>>(x, mask_in, midh, midl);
    gemm_p<<<gN512, blk256, 0, stream>>>(midh, midl, f1h, f1l, enc_b1, enc_a1, NP, NP,
                                         hnh, hnl, NP, NP, NP, DMODEL, 2*DMODEL, MODE_BF);
    // enc2: h = prelu(. @ enc_w2 + b2) + pe
    gemm_p<<<gN512, blk256, 0, stream>>>(hnh, hnl, qkvh, qkvl, enc_b2, enc_a2, pe, h,
                                         NP, NP, NP, NP, NP, DMODEL, DMODEL, MODE_F32);

    for (int i = 0; i < NLAYER; i++) {
        const size_t wofs = (size_t)i * DMODEL * DMODEL;
        wcvt<<<dim3(8, 8), blk256, 0, stream>>>(wq + wofs, qkvh, qkvl, 512, 512);
        wcvt<<<dim3(8, 8), blk256, 0, stream>>>(wk + wofs, qkvh + 512*512, qkvl + 512*512, 512, 512);
        wcvt<<<dim3(8, 8), blk256, 0, stream>>>(wv + wofs, qkvh + 1024*512, qkvl + 1024*512, 512, 512);
        wcvt<<<dim3(8, 8), blk256, 0, stream>>>(wo + wofs, woh, wol, 512, 512);
        wcvt<<<dim3(32, 8), blk256, 0, stream>>>(fw1 + (size_t)i*DMODEL*DFF, f1h, f1l, 2048, 512);
        wcvt<<<dim3(8, 32), blk256, 0, stream>>>(fw2 + (size_t)i*DFF*DMODEL, f2h, f2l, 512, 2048);

        ln_kernel<<<dim3(NTOK), blk64, 0, stream>>>(h, ln_g, ln_b, hnh, hnl);
        gemm_p<<<gQKV, blk256, 0, stream>>>(hnh, hnl, qkvh, qkvl, NP, NP, NP, NP,
                                            qhg, qmg, kg, vhg, vlg, 1536, DMODEL, MODE_QKV);
        attn_mfma<<<dim3(TT/64, NHEAD, BB), blk256, 0, stream>>>(
            (const _Float16*)qhg, (const _Float16*)qmg, (const _Float16*)kg,
            (const _Float16*)vhg, (const _Float16*)vlg,
            (const _Float16*)Ehi, (const _Float16*)Elo, mk, obh, obl);
        gemm_p<<<gN512, blk256, 0, stream>>>(obh, obl, woh, wol, wob + (size_t)i*DMODEL,
                                             NP, h, h, NP, NP, NP, NP, NP, DMODEL, DMODEL, MODE_F32);
        ln_kernel<<<dim3(NTOK), blk64, 0, stream>>>(h, ln_g, ln_b, hnh, hnl);
        gemm_p<<<gFFN1, blk256, 0, stream>>>(hnh, hnl, f1h, f1l, fb1 + (size_t)i*DFF, fa + i,
                                             NP, NP, midh, midl, NP, NP, NP, DFF, DMODEL, MODE_BF);
        gemm_p<<<gN512, blk256, 0, stream>>>(midh, midl, f2h, f2l, fb2 + (size_t)i*DMODEL,
                                             NP, h, h, NP, NP, NP, NP, NP, DMODEL, DFF, MODE_F32);
    }
    // decoder
    wcvt<<<dim3(8, 8), blk256, 0, stream>>>(dw1, woh, wol, 512, 512);
    wcvt<<<dim3(4, 8), blk256, 0, stream>>>(dw2, f2h, f2l, 256, 512);
    cvt_pair<<<dim3(SZ_TD/1024), blk256, 0, stream>>>(h, hnh, hnl);
    gemm_p<<<gN512, blk256, 0, stream>>>(hnh, hnl, woh, wol, db1, da, NP, NP,
                                         midh, midl, NP, NP, NP, DMODEL, DMODEL, MODE_BF);
    gemm_p<<<gN256, blk256, 0, stream>>>(midh, midl, f2h, f2l, db2, NP, NP, out,
                                         NP, NP, NP, NP, NP, MFOUT, DMODEL, MODE_F32);
    #undef NP
}

// Round 8
// 2311.506 us; speedup vs baseline: 1.5204x; 1.5204x over previous
//
#include <hip/hip_runtime.h>
#include <cstddef>

#define BB 4
#define TT 1024
#define DMODEL 512
#define DFF 2048
#define NHEAD 8
#define HDIM 64
#define NTOK (BB*TT)
#define NLAYER 6
#define MFOUT 256
#define LDS_STRIDE 72

typedef __attribute__((ext_vector_type(8))) _Float16 f16x8;
typedef __attribute__((ext_vector_type(8))) short bf16x8;
typedef __attribute__((ext_vector_type(4))) float f32x4;
#define MFMAH(a,b,c) __builtin_amdgcn_mfma_f32_16x16x32_f16(a,b,c,0,0,0)
#define MFMAB(a,b,c) __builtin_amdgcn_mfma_f32_16x16x32_bf16(a,b,c,0,0,0)

union F16U { _Float16 h; unsigned short u; };

__device__ __forceinline__ unsigned f2bf(float f) {
    union { float f; unsigned u; } v; v.f = f;
    return (v.u + 0x7FFFu + ((v.u >> 16) & 1u)) >> 16;
}
__device__ __forceinline__ float bf2f(unsigned h) {
    union { unsigned u; float f; } v; v.u = h << 16;
    return v.f;
}
__device__ __forceinline__ unsigned short f16u(float v) {
    F16U t; t.h = (_Float16)v; return t.u;
}

#define MODE_F32  0   // fp32 out (+optional res)
#define MODE_BF   1   // bf16 hi/lo pair
#define MODE_QKV  5   // gn<512: Q(f16 hi+mid*1024); <1024: K(f16); else V TRANSPOSED (f16 hi/lo planes)

// ---------------- weight convert: fp32 [K][N] -> bf16 hi/lo [N][K] ----------------
__global__ __launch_bounds__(256)
void wcvt(const float* __restrict__ W, unsigned short* __restrict__ Wh,
          unsigned short* __restrict__ Wl, int N, int K)
{
    __shared__ unsigned short Hs[64][LDS_STRIDE];
    __shared__ unsigned short Ls[64][LDS_STRIDE];
    const int tid = threadIdx.x;
    const int n0 = blockIdx.x * 64, k0 = blockIdx.y * 64;
    #pragma unroll
    for (int i = 0; i < 4; i++) {
        const int idx = tid + i * 256;
        const int r = idx >> 4, c4 = (idx & 15) * 4;
        const float4 v = *(const float4*)&W[(size_t)(k0 + r) * N + n0 + c4];
        const float va[4] = {v.x, v.y, v.z, v.w};
        #pragma unroll
        for (int j = 0; j < 4; j++) {
            const unsigned h = f2bf(va[j]);
            Hs[c4 + j][r] = (unsigned short)h;
            Ls[c4 + j][r] = (unsigned short)f2bf(va[j] - bf2f(h));
        }
    }
    __syncthreads();
    #pragma unroll
    for (int i = 0; i < 2; i++) {
        const int idx = tid + i * 256;
        const int r = idx >> 3, c8 = (idx & 7) * 8;
        *(uint4*)&Wh[(size_t)(n0 + r) * K + k0 + c8] = *(const uint4*)&Hs[r][c8];
        *(uint4*)&Wl[(size_t)(n0 + r) * K + k0 + c8] = *(const uint4*)&Ls[r][c8];
    }
}

// ---------------- LDS-staged pair GEMM, bf16 hi/lo 3-pass ----------------
// A: bf16 pair [M][K]; W: bf16 pair [N][K] (pre-converted). Tile 64x64, 4 waves (2x2),
// BK=64 (2 MFMA sub-steps per barrier pair). Staging = pure uint4 copies.
__global__ __launch_bounds__(256)
void gemm_l(const unsigned short* __restrict__ Ah, const unsigned short* __restrict__ Al,
            const unsigned short* __restrict__ Wh, const unsigned short* __restrict__ Wl,
            const float* __restrict__ bias, const float* __restrict__ alpha,
            const float* __restrict__ res, float* __restrict__ outf,
            unsigned short* __restrict__ o1, unsigned short* __restrict__ o2,
            unsigned short* __restrict__ o3, unsigned short* __restrict__ o4,
            unsigned short* __restrict__ o5, int N, int K, int mode)
{
    __shared__ __align__(16) unsigned short Ahs[64*LDS_STRIDE];
    __shared__ __align__(16) unsigned short Als[64*LDS_STRIDE];
    __shared__ __align__(16) unsigned short Whs[64*LDS_STRIDE];
    __shared__ __align__(16) unsigned short Wls[64*LDS_STRIDE];
    const int tid = threadIdx.x;
    const int lane = tid & 63, w = tid >> 6;
    const int wm = w >> 1, wn = w & 1;
    const int quad = lane >> 4, c = lane & 15;
    const int m0 = blockIdx.y * 64, n0 = blockIdx.x * 64;
    const int sr = tid >> 2, sc = (tid & 3) * 16;   // stage: 4 threads/row, 16 shorts each

    f32x4 acc[2][2];
    #pragma unroll
    for (int mi = 0; mi < 2; mi++)
        #pragma unroll
        for (int ni = 0; ni < 2; ni++) { acc[mi][ni][0]=0.f; acc[mi][ni][1]=0.f; acc[mi][ni][2]=0.f; acc[mi][ni][3]=0.f; }

    for (int k0 = 0; k0 < K; k0 += 64) {
        // stage A/W pairs: 2 uint4 per thread per component, coalesced
        const size_t ga = (size_t)(m0 + sr) * K + k0 + sc;
        const size_t gb = (size_t)(n0 + sr) * K + k0 + sc;
        const int ls = sr * LDS_STRIDE + sc;
        *(uint4*)&Ahs[ls]     = *(const uint4*)&Ah[ga];
        *(uint4*)&Ahs[ls + 8] = *(const uint4*)&Ah[ga + 8];
        *(uint4*)&Als[ls]     = *(const uint4*)&Al[ga];
        *(uint4*)&Als[ls + 8] = *(const uint4*)&Al[ga + 8];
        *(uint4*)&Whs[ls]     = *(const uint4*)&Wh[gb];
        *(uint4*)&Whs[ls + 8] = *(const uint4*)&Wh[gb + 8];
        *(uint4*)&Wls[ls]     = *(const uint4*)&Wl[gb];
        *(uint4*)&Wls[ls + 8] = *(const uint4*)&Wl[gb + 8];
        __syncthreads();
        #pragma unroll
        for (int s = 0; s < 2; s++) {
            const int ao = (wm * 32 + c) * LDS_STRIDE + s * 32 + quad * 8;
            const int bo = (wn * 32 + c) * LDS_STRIDE + s * 32 + quad * 8;
            const bf16x8 ah0 = *(const bf16x8*)&Ahs[ao];
            const bf16x8 ah1 = *(const bf16x8*)&Ahs[ao + 16 * LDS_STRIDE];
            const bf16x8 al0 = *(const bf16x8*)&Als[ao];
            const bf16x8 al1 = *(const bf16x8*)&Als[ao + 16 * LDS_STRIDE];
            const bf16x8 bh0 = *(const bf16x8*)&Whs[bo];
            const bf16x8 bh1 = *(const bf16x8*)&Whs[bo + 16 * LDS_STRIDE];
            const bf16x8 bl0 = *(const bf16x8*)&Wls[bo];
            const bf16x8 bl1 = *(const bf16x8*)&Wls[bo + 16 * LDS_STRIDE];
            acc[0][0] = MFMAB(ah0, bh0, acc[0][0]);
            acc[0][1] = MFMAB(ah0, bh1, acc[0][1]);
            acc[1][0] = MFMAB(ah1, bh0, acc[1][0]);
            acc[1][1] = MFMAB(ah1, bh1, acc[1][1]);
            acc[0][0] = MFMAB(al0, bh0, acc[0][0]);
            acc[0][1] = MFMAB(al0, bh1, acc[0][1]);
            acc[1][0] = MFMAB(al1, bh0, acc[1][0]);
            acc[1][1] = MFMAB(al1, bh1, acc[1][1]);
            acc[0][0] = MFMAB(ah0, bl0, acc[0][0]);
            acc[0][1] = MFMAB(ah0, bl1, acc[0][1]);
            acc[1][0] = MFMAB(ah1, bl0, acc[1][0]);
            acc[1][1] = MFMAB(ah1, bl1, acc[1][1]);
        }
        __syncthreads();
    }
    const float alv = alpha ? alpha[0] : 0.f;
    #pragma unroll
    for (int mi = 0; mi < 2; mi++)
        #pragma unroll
        for (int ni = 0; ni < 2; ni++) {
            const int gn = n0 + wn * 32 + ni * 16 + c;
            const int gmb = m0 + wm * 32 + mi * 16 + quad * 4;
            const float bv = bias ? bias[gn] : 0.f;
            float v4[4];
            #pragma unroll
            for (int r = 0; r < 4; r++) {
                float v = acc[mi][ni][r] + bv;
                if (alpha) v = (v >= 0.f) ? v : alv * v;
                v4[r] = v;
            }
            if (mode == MODE_F32) {
                #pragma unroll
                for (int r = 0; r < 4; r++) {
                    const size_t oix = (size_t)(gmb + r) * N + gn;
                    outf[oix] = v4[r] + (res ? res[oix] : 0.f);
                }
            } else if (mode == MODE_BF) {
                #pragma unroll
                for (int r = 0; r < 4; r++) {
                    const size_t oix = (size_t)(gmb + r) * N + gn;
                    const unsigned h = f2bf(v4[r]);
                    o1[oix] = (unsigned short)h;
                    o2[oix] = (unsigned short)f2bf(v4[r] - bf2f(h));
                }
            } else { // MODE_QKV
                const int seg = gn >> 9;   // uniform per (block, wn)
                if (seg == 0) {
                    #pragma unroll
                    for (int r = 0; r < 4; r++) {
                        const size_t qix = (size_t)(gmb + r) * 512 + gn;
                        F16U t; t.h = (_Float16)v4[r];
                        o1[qix] = t.u;
                        o2[qix] = f16u((v4[r] - (float)t.h) * 1024.f);
                    }
                } else if (seg == 1) {
                    #pragma unroll
                    for (int r = 0; r < 4; r++)
                        o3[(size_t)(gmb + r) * 512 + (gn - 512)] = f16u(v4[r]);
                } else {
                    // V transposed: planes [(bb*8+h)*64 + d][t], 4 consecutive t -> 8B store
                    const int d512 = gn - 1024;
                    const int bbp = gmb >> 10, t0 = gmb & 1023;
                    const size_t vix = ((size_t)(bbp * 8 + (d512 >> 6)) * 64 + (d512 & 63)) * 1024 + t0;
                    ushort4 hv, lv;
                    unsigned short* hp = (unsigned short*)&hv;
                    unsigned short* lp = (unsigned short*)&lv;
                    #pragma unroll
                    for (int r = 0; r < 4; r++) {
                        F16U t; t.h = (_Float16)v4[r];
                        hp[r] = t.u;
                        lp[r] = f16u(v4[r] - (float)t.h);
                    }
                    *(ushort4*)&o4[vix] = hv;
                    *(ushort4*)&o5[vix] = lv;
                }
            }
        }
}

// ---------------- LayerNorm: one wave per token -> bf16 hi/lo pair ----------------
__global__ __launch_bounds__(64)
void ln_kernel(const float* __restrict__ x, const float* __restrict__ g,
               const float* __restrict__ b, unsigned short* __restrict__ oh,
               unsigned short* __restrict__ ol)
{
    const int token = blockIdx.x;
    const int lane = threadIdx.x;
    const float* row = x + (size_t)token * DMODEL;
    float v[8];
    *(float4*)&v[0] = *(const float4*)&row[lane * 4];
    *(float4*)&v[4] = *(const float4*)&row[256 + lane * 4];
    float s = 0.f, s2 = 0.f;
    #pragma unroll
    for (int i = 0; i < 8; i++) { s += v[i]; s2 += v[i] * v[i]; }
    #pragma unroll
    for (int off = 1; off < 64; off <<= 1) {
        s  += __shfl_xor(s, off);
        s2 += __shfl_xor(s2, off);
    }
    const float mean = s * (1.f / DMODEL);
    const float var  = s2 * (1.f / DMODEL) - mean * mean;
    const float rstd = rsqrtf(var + 1e-5f);
    #pragma unroll
    for (int hh = 0; hh < 2; hh++) {
        const int base = hh * 256 + lane * 4;
        const float4 gv = *(const float4*)&g[base];
        const float4 bv = *(const float4*)&b[base];
        float o[4];
        o[0] = (v[hh*4+0] - mean) * rstd * gv.x + bv.x;
        o[1] = (v[hh*4+1] - mean) * rstd * gv.y + bv.y;
        o[2] = (v[hh*4+2] - mean) * rstd * gv.z + bv.z;
        o[3] = (v[hh*4+3] - mean) * rstd * gv.w + bv.w;
        ushort4 ph, pl;
        unsigned short* php = (unsigned short*)&ph;
        unsigned short* plp = (unsigned short*)&pl;
        #pragma unroll
        for (int j = 0; j < 4; j++) {
            const unsigned hb = f2bf(o[j]);
            php[j] = (unsigned short)hb;
            plp[j] = (unsigned short)f2bf(o[j] - bf2f(hb));
        }
        *(ushort4*)&oh[(size_t)token * DMODEL + base] = ph;
        *(ushort4*)&ol[(size_t)token * DMODEL + base] = pl;
    }
}

// ---------------- fp32 -> bf16 hi/lo pair (elementwise) ----------------
__global__ __launch_bounds__(256)
void cvt_pair(const float* __restrict__ x, unsigned short* __restrict__ oh,
              unsigned short* __restrict__ ol)
{
    const int idx = (blockIdx.x * 256 + threadIdx.x) * 4;
    const float4 v = *(const float4*)&x[idx];
    const float va[4] = {v.x, v.y, v.z, v.w};
    ushort4 ph, pl;
    unsigned short* php = (unsigned short*)&ph;
    unsigned short* plp = (unsigned short*)&pl;
    #pragma unroll
    for (int j = 0; j < 4; j++) {
        const unsigned hb = f2bf(va[j]);
        php[j] = (unsigned short)hb;
        plp[j] = (unsigned short)f2bf(va[j] - bf2f(hb));
    }
    *(ushort4*)&oh[idx] = ph;
    *(ushort4*)&ol[idx] = pl;
}

// ---------------- concat [x | mask] -> bf16 pair, [4096][1024] ----------------
__global__ __launch_bounds__(256)
void cvt_cat(const float* __restrict__ x, const float* __restrict__ mask,
             unsigned short* __restrict__ oh, unsigned short* __restrict__ ol)
{
    const int idx = (blockIdx.x * 256 + threadIdx.x) * 4;
    const int row = idx >> 10, col = idx & 1023;
    const float* src = (col < 512) ? &x[(size_t)row * 512 + col]
                                   : &mask[(size_t)row * 512 + col - 512];
    const float4 v = *(const float4*)src;
    const float va[4] = {v.x, v.y, v.z, v.w};
    ushort4 ph, pl;
    unsigned short* php = (unsigned short*)&ph;
    unsigned short* plp = (unsigned short*)&pl;
    #pragma unroll
    for (int j = 0; j < 4; j++) {
        const unsigned hb = f2bf(va[j]);
        php[j] = (unsigned short)hb;
        plp[j] = (unsigned short)f2bf(va[j] - bf2f(hb));
    }
    *(ushort4*)&oh[idx] = ph;
    *(ushort4*)&ol[idx] = pl;
}

// ---------------- attention key-validity mask ----------------
__global__ __launch_bounds__(64)
void mask_kernel(const float* __restrict__ mask_in, float* __restrict__ mk)
{
    const int token = blockIdx.x;
    const int lane = threadIdx.x;
    const float* row = mask_in + (size_t)token * DMODEL;
    const float4 a = *(const float4*)&row[lane * 4];
    const float4 c = *(const float4*)&row[256 + lane * 4];
    float s = a.x + a.y + a.z + a.w + c.x + c.y + c.z + c.w;
    #pragma unroll
    for (int off = 1; off < 64; off <<= 1) s += __shfl_xor(s, off);
    if (lane == 0) mk[token] = (s > 0.f) ? 0.f : -1e9f;
}

// ---------------- relative position table E -> f16 hi/lo (2047, 64) ----------------
__global__ __launch_bounds__(64)
void e_kernel(const float* __restrict__ w1, const float* __restrict__ b1,
              const float* __restrict__ a1, const float* __restrict__ w2,
              const float* __restrict__ b2,
              unsigned short* __restrict__ Ehi, unsigned short* __restrict__ Elo)
{
    __shared__ float t1[DMODEL];
    const int r = blockIdx.x;
    const int lane = threadIdx.x;
    const float rel = (float)r - 1023.f;
    const float al = a1[0];
    for (int j = lane; j < DMODEL; j += 64) {
        float v = rel * w1[j] + b1[j];
        t1[j] = (v >= 0.f) ? v : al * v;
    }
    __syncthreads();
    float acc = b2[lane];
    for (int j = 0; j < DMODEL; j++)
        acc = fmaf(t1[j], w2[j * HDIM + lane], acc);
    F16U t; t.h = (_Float16)acc;
    Ehi[(size_t)r * HDIM + lane] = t.u;
    Elo[(size_t)r * HDIM + lane] = f16u(acc - (float)t.h);
}

// ---------------- keyframe encoder layer 1 (K=2) -> bf16 pair ----------------
__global__ __launch_bounds__(256)
void kf1_kernel(const float* __restrict__ p, const float* __restrict__ w1,
                const float* __restrict__ b1, const float* __restrict__ a1,
                unsigned short* __restrict__ oh, unsigned short* __restrict__ ol)
{
    const int idx = blockIdx.x * 256 + threadIdx.x;
    const int m = idx >> 9, n = idx & 511;
    float v = fmaf(p[m*2], w1[n], fmaf(p[m*2+1], w1[DMODEL + n], b1[n]));
    v = (v >= 0.f) ? v : a1[0] * v;
    const unsigned hb = f2bf(v);
    oh[idx] = (unsigned short)hb;
    ol[idx] = (unsigned short)f2bf(v - bf2f(hb));
}

// ---------------- BARRIER-FREE MFMA flash attention ----------------
// Q [tok][d] f16 hi+mid; K [tok][d] f16 (already B-frag layout); V TRANSPOSED planes
// [(b*8+h)*64+d][t] f16 hi/lo (B-frag layout for PV); E direct global. Only P goes
// through LDS (per-wave-private rows, __threadfence_block both directions). No __syncthreads.
__global__ __launch_bounds__(256)
void attn_mfma(const _Float16* __restrict__ qhg, const _Float16* __restrict__ qmg,
               const _Float16* __restrict__ kg, const _Float16* __restrict__ vth,
               const _Float16* __restrict__ vtl, const _Float16* __restrict__ Ehi,
               const _Float16* __restrict__ Elo, const float* __restrict__ mk,
               unsigned short* __restrict__ obh, unsigned short* __restrict__ obl)
{
    __shared__ __align__(16) _Float16 Phs[64*LDS_STRIDE];
    __shared__ __align__(16) _Float16 Pls[64*LDS_STRIDE];

    const int tid = threadIdx.x;
    const int lane = tid & 63;
    const int w = tid >> 6;
    const int quad = lane >> 4;
    const int c = lane & 15;
    const int q0 = blockIdx.x * 64;
    const int hh = blockIdx.y;
    const int bb = blockIdx.z;
    const size_t base = (size_t)bb * TT * DMODEL + (size_t)hh * HDIM;
    const size_t vbase = (size_t)(bb * NHEAD + hh) * HDIM * TT;
    const float* mkp = mk + bb * TT;

    f16x8 qh[2], qm[2];
    {
        const size_t qrow = base + (size_t)(q0 + 16 * w + c) * DMODEL;
        #pragma unroll
        for (int s = 0; s < 2; s++) {
            qh[s] = *(const f16x8*)&qhg[qrow + s * 32 + quad * 8];
            qm[s] = *(const f16x8*)&qmg[qrow + s * 32 + quad * 8];
        }
    }

    f32x4 O[4];
    #pragma unroll
    for (int dt = 0; dt < 4; dt++) { O[dt][0]=0.f; O[dt][1]=0.f; O[dt][2]=0.f; O[dt][3]=0.f; }
    float mrun[4] = {-1e30f, -1e30f, -1e30f, -1e30f};
    float lrun[4] = {0.f, 0.f, 0.f, 0.f};
    const int Jb = 48 - 16 * w;

    for (int kt = 0; kt < 16; kt++) {
        const int k0 = kt * 64;
        const int rbase = k0 - q0 + 960;

        // S = Q K^T : K fragments direct from global (already B-layout)
        f32x4 S[4];
        #pragma unroll
        for (int t = 0; t < 4; t++) { S[t][0]=0.f; S[t][1]=0.f; S[t][2]=0.f; S[t][3]=0.f; }
        #pragma unroll
        for (int t = 0; t < 4; t++) {
            const size_t krow = base + (size_t)(k0 + 16 * t + c) * DMODEL + quad * 8;
            #pragma unroll
            for (int s = 0; s < 2; s++) {
                const f16x8 kf = *(const f16x8*)&kg[krow + s * 32];
                S[t] = MFMAH(qh[s], kf, S[t]);
            }
        }
        // rel term: R = Qh.Eh + Qh.El ; R2 = Qm.Eh (recombined /1024)
        f32x4 R[5], R2[5];
        #pragma unroll
        for (int u = 0; u < 5; u++) {
            R[u][0]=0.f; R[u][1]=0.f; R[u][2]=0.f; R[u][3]=0.f;
            R2[u][0]=0.f; R2[u][1]=0.f; R2[u][2]=0.f; R2[u][3]=0.f;
        }
        #pragma unroll
        for (int u = 0; u < 5; u++) {
            int gr = rbase + Jb + 16 * u + c;
            gr = gr < 0 ? 0 : (gr > 2046 ? 2046 : gr);
            const size_t eb = (size_t)gr * HDIM;
            const f16x8 eh0 = *(const f16x8*)&Ehi[eb + quad * 8];
            const f16x8 eh1 = *(const f16x8*)&Ehi[eb + 32 + quad * 8];
            const f16x8 el0 = *(const f16x8*)&Elo[eb + quad * 8];
            const f16x8 el1 = *(const f16x8*)&Elo[eb + 32 + quad * 8];
            R[u]  = MFMAH(qh[0], eh0, R[u]);
            R[u]  = MFMAH(qh[1], eh1, R[u]);
            R[u]  = MFMAH(qh[0], el0, R[u]);
            R[u]  = MFMAH(qh[1], el1, R[u]);
            R2[u] = MFMAH(qm[0], eh0, R2[u]);
            R2[u] = MFMAH(qm[1], eh1, R2[u]);
        }
        #pragma unroll
        for (int u = 0; u < 5; u++)
            #pragma unroll
            for (int r = 0; r < 4; r++)
                R[u][r] = fmaf(R2[u][r], 9.765625e-4f, R[u][r]);
        // skew gather via bpermute: jj = kl - q + 15
        float bp[4][5];
        #pragma unroll
        for (int r = 0; r < 4; r++) {
            const int q = quad * 4 + r;
            const int srcl = (quad << 4) | ((c - q + 15) & 15);
            #pragma unroll
            for (int u = 0; u < 5; u++)
                bp[r][u] = __int_as_float(__builtin_amdgcn_ds_bpermute(srcl << 2, __float_as_int(R[u][r])));
        }
        float mkv[4];
        #pragma unroll
        for (int t = 0; t < 4; t++) mkv[t] = mkp[k0 + 16*t + c];
        float scv[4][4];
        float tmax[4] = {-3e38f, -3e38f, -3e38f, -3e38f};
        #pragma unroll
        for (int t = 0; t < 4; t++)
            #pragma unroll
            for (int r = 0; r < 4; r++) {
                const int q = quad*4 + r;
                const int jj = 16*t + c - q + 15;
                const float rv = ((jj >> 4) == t) ? bp[r][t] : bp[r][t+1];
                const float v = (S[t][r] + rv) * 0.125f + mkv[t];
                scv[t][r] = v;
                tmax[r] = fmaxf(tmax[r], v);
            }
        #pragma unroll
        for (int r = 0; r < 4; r++) {
            tmax[r] = fmaxf(tmax[r], __shfl_xor(tmax[r], 1));
            tmax[r] = fmaxf(tmax[r], __shfl_xor(tmax[r], 2));
            tmax[r] = fmaxf(tmax[r], __shfl_xor(tmax[r], 4));
            tmax[r] = fmaxf(tmax[r], __shfl_xor(tmax[r], 8));
        }
        float corr[4];
        #pragma unroll
        for (int r = 0; r < 4; r++) {
            const float mn = fmaxf(mrun[r], tmax[r]);
            corr[r] = __expf(mrun[r] - mn);
            mrun[r] = mn;
            lrun[r] *= corr[r];
        }
        #pragma unroll
        for (int dt = 0; dt < 4; dt++)
            #pragma unroll
            for (int r = 0; r < 4; r++) O[dt][r] *= corr[r];
        float psum[4] = {0.f, 0.f, 0.f, 0.f};
        #pragma unroll
        for (int t = 0; t < 4; t++)
            #pragma unroll
            for (int r = 0; r < 4; r++) {
                const float p = __expf(scv[t][r] - mrun[r]);
                psum[r] += p;
                const _Float16 hp = (_Float16)p;
                Phs[(w*16 + quad*4 + r)*LDS_STRIDE + 16*t + c] = hp;
                Pls[(w*16 + quad*4 + r)*LDS_STRIDE + 16*t + c] = (_Float16)(p - (float)hp);
            }
        #pragma unroll
        for (int r = 0; r < 4; r++) {
            psum[r] += __shfl_xor(psum[r], 1);
            psum[r] += __shfl_xor(psum[r], 2);
            psum[r] += __shfl_xor(psum[r], 4);
            psum[r] += __shfl_xor(psum[r], 8);
            lrun[r] += psum[r];
        }
        __threadfence_block();   // order P write -> P read (same wave, cross-lane)
        f16x8 pfh[2], pfl[2];
        #pragma unroll
        for (int s = 0; s < 2; s++) {
            pfh[s] = *(const f16x8*)&Phs[(w*16 + c)*LDS_STRIDE + s*32 + quad*8];
            pfl[s] = *(const f16x8*)&Pls[(w*16 + c)*LDS_STRIDE + s*32 + quad*8];
        }
        __threadfence_block();   // order P read(t) -> P write(t+1)
        // O += P V : V fragments direct from transposed planes (B-layout)
        #pragma unroll
        for (int dt = 0; dt < 4; dt++) {
            const size_t vrow = vbase + (size_t)(16 * dt + c) * TT + k0 + quad * 8;
            #pragma unroll
            for (int s = 0; s < 2; s++) {
                const f16x8 vhf = *(const f16x8*)&vth[vrow + s * 32];
                const f16x8 vlf = *(const f16x8*)&vtl[vrow + s * 32];
                O[dt] = MFMAH(pfh[s], vhf, O[dt]);
                O[dt] = MFMAH(pfl[s], vhf, O[dt]);
                O[dt] = MFMAH(pfh[s], vlf, O[dt]);
            }
        }
    }
    float inv[4];
    #pragma unroll
    for (int r = 0; r < 4; r++) inv[r] = 1.f / lrun[r];
    #pragma unroll
    for (int dt = 0; dt < 4; dt++)
        #pragma unroll
        for (int r = 0; r < 4; r++) {
            const float v = O[dt][r] * inv[r];
            const size_t oix = base + (size_t)(q0 + 16*w + quad*4 + r) * DMODEL + 16*dt + c;
            const unsigned hb = f2bf(v);
            obh[oix] = (unsigned short)hb;
            obl[oix] = (unsigned short)f2bf(v - bf2f(hb));
        }
}

extern "C" void kernel_launch(void* const* d_in, const int* in_sizes, int n_in,
                              void* d_out, int out_size, void* d_ws, size_t ws_size,
                              hipStream_t stream)
{
    const float* x       = (const float*)d_in[0];
    const float* mask_in = (const float*)d_in[1];
    const float* p_kf    = (const float*)d_in[2];
    const float* enc_w1  = (const float*)d_in[3];
    const float* enc_b1  = (const float*)d_in[4];
    const float* enc_a1  = (const float*)d_in[5];
    const float* enc_w2  = (const float*)d_in[6];
    const float* enc_b2  = (const float*)d_in[7];
    const float* enc_a2  = (const float*)d_in[8];
    const float* kf_w1   = (const float*)d_in[9];
    const float* kf_b1   = (const float*)d_in[10];
    const float* kf_a    = (const float*)d_in[11];
    const float* kf_w2   = (const float*)d_in[12];
    const float* kf_b2   = (const float*)d_in[13];
    const float* rel_w1  = (const float*)d_in[14];
    const float* rel_b1  = (const float*)d_in[15];
    const float* rel_a   = (const float*)d_in[16];
    const float* rel_w2  = (const float*)d_in[17];
    const float* rel_b2  = (const float*)d_in[18];
    const float* ln_g    = (const float*)d_in[19];
    const float* ln_b    = (const float*)d_in[20];
    const float* wq      = (const float*)d_in[21];
    const float* wk      = (const float*)d_in[22];
    const float* wv      = (const float*)d_in[23];
    const float* wo      = (const float*)d_in[24];
    const float* wob     = (const float*)d_in[25];
    const float* fw1     = (const float*)d_in[26];
    const float* fb1     = (const float*)d_in[27];
    const float* fa      = (const float*)d_in[28];
    const float* fw2     = (const float*)d_in[29];
    const float* fb2     = (const float*)d_in[30];
    const float* dw1     = (const float*)d_in[31];
    const float* db1     = (const float*)d_in[32];
    const float* da      = (const float*)d_in[33];
    const float* dw2     = (const float*)d_in[34];
    const float* db2     = (const float*)d_in[35];
    float* out = (float*)d_out;

    // ---- workspace layout (bytes), total ~88.6 MB ----
    char* p = (char*)d_ws;
    const size_t SZ_TD  = (size_t)NTOK * DMODEL;      // 2M elems
    float* h = (float*)p;                 p += SZ_TD * 4;
    unsigned short* hnh = (unsigned short*)p; p += SZ_TD * 2;
    unsigned short* hnl = (unsigned short*)p; p += SZ_TD * 2;
    unsigned short* qhg = (unsigned short*)p; p += SZ_TD * 2;
    unsigned short* qmg = (unsigned short*)p; p += SZ_TD * 2;
    unsigned short* kg  = (unsigned short*)p; p += SZ_TD * 2;
    unsigned short* vhg = (unsigned short*)p; p += SZ_TD * 2;   // V^T hi planes
    unsigned short* vlg = (unsigned short*)p; p += SZ_TD * 2;   // V^T lo planes
    unsigned short* obh = (unsigned short*)p; p += SZ_TD * 2;
    unsigned short* obl = (unsigned short*)p; p += SZ_TD * 2;
    unsigned short* midh = (unsigned short*)p; p += (size_t)NTOK * DFF * 2;
    unsigned short* midl = (unsigned short*)p; p += (size_t)NTOK * DFF * 2;
    unsigned short* Ehi = (unsigned short*)p; p += (size_t)2048 * HDIM * 2;
    unsigned short* Elo = (unsigned short*)p; p += (size_t)2048 * HDIM * 2;
    float* mk = (float*)p;                p += (size_t)NTOK * 4;
    unsigned short* qkvh = (unsigned short*)p; p += (size_t)1536 * 512 * 2;
    unsigned short* qkvl = (unsigned short*)p; p += (size_t)1536 * 512 * 2;
    unsigned short* woh  = (unsigned short*)p; p += (size_t)512 * 512 * 2;
    unsigned short* wol  = (unsigned short*)p; p += (size_t)512 * 512 * 2;
    unsigned short* f1h  = (unsigned short*)p; p += (size_t)2048 * 512 * 2;
    unsigned short* f1l  = (unsigned short*)p; p += (size_t)2048 * 512 * 2;
    unsigned short* f2h  = (unsigned short*)p; p += (size_t)512 * 2048 * 2;
    unsigned short* f2l  = (unsigned short*)p; p += (size_t)512 * 2048 * 2;
    float* pe = (float*)obh;   // 8 MB spanning obh+obl (free during encode)

    const dim3 blk256(256), blk64(64);
    const dim3 gN512(8, 64);
    const dim3 gQKV(24, 64);
    const dim3 gFFN1(32, 64);
    const dim3 gN256(4, 64);
    #define NP nullptr

    e_kernel<<<dim3(2047), blk64, 0, stream>>>(rel_w1, rel_b1, rel_a, rel_w2, rel_b2, Ehi, Elo);
    mask_kernel<<<dim3(NTOK), blk64, 0, stream>>>(mask_in, mk);
    wcvt<<<dim3(8, 8), blk256, 0, stream>>>(kf_w2, woh, wol, 512, 512);
    wcvt<<<dim3(8, 16), blk256, 0, stream>>>(enc_w1, f1h, f1l, 512, 1024);
    wcvt<<<dim3(8, 8), blk256, 0, stream>>>(enc_w2, qkvh, qkvl, 512, 512);
    kf1_kernel<<<dim3(NTOK*DMODEL/256), blk256, 0, stream>>>(p_kf, kf_w1, kf_b1, kf_a, qhg, qmg);
    gemm_l<<<gN512, blk256, 0, stream>>>(qhg, qmg, woh, wol, kf_b2, NP, NP, pe,
                                         NP, NP, NP, NP, NP, DMODEL, DMODEL, MODE_F32);
    cvt_cat<<<dim3(NTOK*1024/1024), blk256, 0, stream>>>(x, mask_in, midh, midl);
    gemm_l<<<gN512, blk256, 0, stream>>>(midh, midl, f1h, f1l, enc_b1, enc_a1, NP, NP,
                                         hnh, hnl, NP, NP, NP, DMODEL, 2*DMODEL, MODE_BF);
    gemm_l<<<gN512, blk256, 0, stream>>>(hnh, hnl, qkvh, qkvl, enc_b2, enc_a2, pe, h,
                                         NP, NP, NP, NP, NP, DMODEL, DMODEL, MODE_F32);

    for (int i = 0; i < NLAYER; i++) {
        const size_t wofs = (size_t)i * DMODEL * DMODEL;
        wcvt<<<dim3(8, 8), blk256, 0, stream>>>(wq + wofs, qkvh, qkvl, 512, 512);
        wcvt<<<dim3(8, 8), blk256, 0, stream>>>(wk + wofs, qkvh + 512*512, qkvl + 512*512, 512, 512);
        wcvt<<<dim3(8, 8), blk256, 0, stream>>>(wv + wofs, qkvh + 1024*512, qkvl + 1024*512, 512, 512);
        wcvt<<<dim3(8, 8), blk256, 0, stream>>>(wo + wofs, woh, wol, 512, 512);
        wcvt<<<dim3(32, 8), blk256, 0, stream>>>(fw1 + (size_t)i*DMODEL*DFF, f1h, f1l, 2048, 512);
        wcvt<<<dim3(8, 32), blk256, 0, stream>>>(fw2 + (size_t)i*DFF*DMODEL, f2h, f2l, 512, 2048);

        ln_kernel<<<dim3(NTOK), blk64, 0, stream>>>(h, ln_g, ln_b, hnh, hnl);
        gemm_l<<<gQKV, blk256, 0, stream>>>(hnh, hnl, qkvh, qkvl, NP, NP, NP, NP,
                                            qhg, qmg, kg, vhg, vlg, 1536, DMODEL, MODE_QKV);
        attn_mfma<<<dim3(TT/64, NHEAD, BB), blk256, 0, stream>>>(
            (const _Float16*)qhg, (const _Float16*)qmg, (const _Float16*)kg,
            (const _Float16*)vhg, (const _Float16*)vlg,
            (const _Float16*)Ehi, (const _Float16*)Elo, mk, obh, obl);
        gemm_l<<<gN512, blk256, 0, stream>>>(obh, obl, woh, wol, wob + (size_t)i*DMODEL,
                                             NP, h, h, NP, NP, NP, NP, NP, DMODEL, DMODEL, MODE_F32);
        ln_kernel<<<dim3(NTOK), blk64, 0, stream>>>(h, ln_g, ln_b, hnh, hnl);
        gemm_l<<<gFFN1, blk256, 0, stream>>>(hnh, hnl, f1h, f1l, fb1 + (size_t)i*DFF, fa + i,
                                             NP, NP, midh, midl, NP, NP, NP, DFF, DMODEL, MODE_BF);
        gemm_l<<<gN512, blk256, 0, stream>>>(midh, midl, f2h, f2l, fb2 + (size_t)i*DMODEL,
                                             NP, h, h, NP, NP, NP, NP, NP, DMODEL, DFF, MODE_F32);
    }
    wcvt<<<dim3(8, 8), blk256, 0, stream>>>(dw1, woh, wol, 512, 512);
    wcvt<<<dim3(4, 8), blk256, 0, stream>>>(dw2, f2h, f2l, 256, 512);
    cvt_pair<<<dim3(SZ_TD/1024), blk256, 0, stream>>>(h, hnh, hnl);
    gemm_l<<<gN512, blk256, 0, stream>>>(hnh, hnl, woh, wol, db1, da, NP, NP,
                                         midh, midl, NP, NP, NP, DMODEL, DMODEL, MODE_BF);
    gemm_l<<<gN256, blk256, 0, stream>>>(midh, midl, f2h, f2l, db2, NP, NP, out,
                                         NP, NP, NP, NP, NP, MFOUT, DMODEL, MODE_F32);
    #undef NP
}